// Round 1
// baseline (18.386 us; speedup 1.0000x reference)
//
#include <hip/hip_runtime.h>

// Reference: x (64, 4096, 128) f32. window = x[54:64] along axis 0.
// 32 steps: new = mean(window, axis=0); window = shift+append(new).
// Output: (32, 4096, 128) f32. Per-position independent recurrence.

#define SEQ        64
#define NPOS       (4096 * 128)   // 524288 positions per time-slice
#define RA_WINDOW  10
#define HORIZON    32

__global__ __launch_bounds__(256) void rolling_avg_kernel(
    const float* __restrict__ x, float* __restrict__ out)
{
    // Each thread handles 4 consecutive positions via float4 (16 B/lane).
    const int pos4 = blockIdx.x * blockDim.x + threadIdx.x;   // float4 index
    const int nPos4 = NPOS / 4;                               // 131072
    if (pos4 >= nPos4) return;

    const float4* __restrict__ xin =
        reinterpret_cast<const float4*>(x) + (size_t)(SEQ - RA_WINDOW) * nPos4 + pos4;
    float4* __restrict__ o = reinterpret_cast<float4*>(out) + pos4;

    // Load the 10-deep window (coalesced, 16 B/lane).
    float4 w[RA_WINDOW];
    #pragma unroll
    for (int k = 0; k < RA_WINDOW; ++k)
        w[k] = xin[(size_t)k * nPos4];

    // Running sum of the window.
    float4 s;
    s.x = s.y = s.z = s.w = 0.0f;
    #pragma unroll
    for (int k = 0; k < RA_WINDOW; ++k) {
        s.x += w[k].x; s.y += w[k].y; s.z += w[k].z; s.w += w[k].w;
    }

    const float inv = 1.0f / (float)RA_WINDOW;

    // Fully unrolled so w[t % 10] is a compile-time register index.
    #pragma unroll
    for (int t = 0; t < HORIZON; ++t) {
        float4 nw;
        nw.x = s.x * inv; nw.y = s.y * inv; nw.z = s.z * inv; nw.w = s.w * inv;
        o[(size_t)t * nPos4] = nw;
        const int idx = t % RA_WINDOW;
        s.x += nw.x - w[idx].x;
        s.y += nw.y - w[idx].y;
        s.z += nw.z - w[idx].z;
        s.w += nw.w - w[idx].w;
        w[idx] = nw;
    }
}

extern "C" void kernel_launch(void* const* d_in, const int* in_sizes, int n_in,
                              void* d_out, int out_size, void* d_ws, size_t ws_size,
                              hipStream_t stream) {
    const float* x = (const float*)d_in[0];
    float* out = (float*)d_out;

    const int threads = 256;
    const int blocks = (NPOS / 4 + threads - 1) / threads;   // 512
    rolling_avg_kernel<<<blocks, threads, 0, stream>>>(x, out);
}